// Round 3
// baseline (301.480 us; speedup 1.0000x reference)
//
#include <hip/hip_runtime.h>

#define N_ITEMS 65536

// ---------------- Kernel 1: q = x @ W  (1024x1024x1024, fp32) ----------------
__launch_bounds__(256)
__global__ void gemm_q_kernel(const float* __restrict__ A,
                              const float* __restrict__ W,
                              float* __restrict__ C) {
  __shared__ float As[32][68];
  __shared__ float Bs[32][68];
  const int tid = threadIdx.x;
  const int tx = tid & 15, ty = tid >> 4;
  const int rb = blockIdx.y * 64, cb = blockIdx.x * 64;
  const int r0 = tid >> 3, c4 = (tid & 7) << 2;
  const int r1 = r0 + 32;
  const int kk0 = tid >> 4, c4b = (tid & 15) << 2;
  const int kk1 = kk0 + 16;

  float4 va0 = *(const float4*)&A[(rb + r0) * 1024 + c4];
  float4 va1 = *(const float4*)&A[(rb + r1) * 1024 + c4];
  float4 vb0 = *(const float4*)&W[kk0 * 1024 + cb + c4b];
  float4 vb1 = *(const float4*)&W[kk1 * 1024 + cb + c4b];

  float acc[4][4] = {};
  for (int k0 = 0; k0 < 1024; k0 += 32) {
    As[c4 + 0][r0] = va0.x; As[c4 + 1][r0] = va0.y;
    As[c4 + 2][r0] = va0.z; As[c4 + 3][r0] = va0.w;
    As[c4 + 0][r1] = va1.x; As[c4 + 1][r1] = va1.y;
    As[c4 + 2][r1] = va1.z; As[c4 + 3][r1] = va1.w;
    *(float4*)&Bs[kk0][c4b] = vb0;
    *(float4*)&Bs[kk1][c4b] = vb1;
    __syncthreads();
    if (k0 + 32 < 1024) {
      va0 = *(const float4*)&A[(rb + r0) * 1024 + k0 + 32 + c4];
      va1 = *(const float4*)&A[(rb + r1) * 1024 + k0 + 32 + c4];
      vb0 = *(const float4*)&W[(k0 + 32 + kk0) * 1024 + cb + c4b];
      vb1 = *(const float4*)&W[(k0 + 32 + kk1) * 1024 + cb + c4b];
    }
#pragma unroll
    for (int kk = 0; kk < 32; kk++) {
      const float4 a = *(const float4*)&As[kk][ty << 2];
      const float4 b = *(const float4*)&Bs[kk][tx << 2];
      const float ar[4] = {a.x, a.y, a.z, a.w};
      const float br[4] = {b.x, b.y, b.z, b.w};
#pragma unroll
      for (int r = 0; r < 4; r++)
#pragma unroll
        for (int c = 0; c < 4; c++)
          acc[r][c] = fmaf(ar[r], br[c], acc[r][c]);
    }
    __syncthreads();
  }
#pragma unroll
  for (int r = 0; r < 4; r++) {
    const float4 v = make_float4(acc[r][0], acc[r][1], acc[r][2], acc[r][3]);
    *(float4*)&C[(rb + (ty << 2) + r) * 1024 + cb + (tx << 2)] = v;
  }
}

// ---------------- Kernel 2: prep — q_sq, c_sq, packed codes + LDS offsets ----
// poffs: per item, 8 u16 byte-offsets into the 32-replica scan table:
//   h = (m&3)<<14 | (c>>1)<<7 | (c&1)<<1   (max 65410, fits u16)
// pcodes kept for the 64KB fallback scan.
__launch_bounds__(256)
__global__ void prep_kernel(const float* __restrict__ q,
                            const float* __restrict__ kcb,
                            const int* __restrict__ key_codes,
                            float* __restrict__ qsq,
                            float* __restrict__ csq,
                            unsigned long long* __restrict__ pcodes,
                            uint4* __restrict__ poffs) {
  const int gid = blockIdx.x * 256 + threadIdx.x;
  if (gid < N_ITEMS) {
    unsigned long long p = 0ull;
    unsigned h[8];
#pragma unroll
    for (int j = 0; j < 8; j++) {
      const unsigned c = (unsigned)key_codes[gid * 8 + j] & 255u;
      p |= (unsigned long long)c << (8 * j);
      h[j] = ((unsigned)(j & 3) << 14) | ((c >> 1) << 7) | ((c & 1u) << 1);
    }
    pcodes[gid] = p;
    poffs[gid] = make_uint4(h[0] | (h[1] << 16), h[2] | (h[3] << 16),
                            h[4] | (h[5] << 16), h[6] | (h[7] << 16));
  }
  if (gid < 8192) {
    const float* p = &q[(gid >> 3) * 1024 + (gid & 7) * 128];
    float s = 0.f;
#pragma unroll 4
    for (int k = 0; k < 128; k++) s = fmaf(p[k], p[k], s);
    qsq[gid] = s;
  }
  if (gid < 2048) {
    const float* p = &kcb[gid * 128];
    float s = 0.f;
#pragma unroll 4
    for (int k = 0; k < 128; k++) s = fmaf(p[k], p[k], s);
    csq[gid] = s;
  }
}

// ---------------- Kernel 3: lut[b][m*256+c] = qsq + csq - 2*qs.cb ----------------
__launch_bounds__(256)
__global__ void lut_kernel(const float* __restrict__ q,
                           const float* __restrict__ kcb,
                           const float* __restrict__ qsq,
                           const float* __restrict__ csq,
                           float* __restrict__ lut) {
  __shared__ float As[32][68];
  __shared__ float Bs[32][68];
  const int tid = threadIdx.x;
  const int tx = tid & 15, ty = tid >> 4;
  const int m = blockIdx.z;
  const int rb = blockIdx.y * 64;
  const int cb0 = blockIdx.x * 64;
  float acc[4][4] = {};
  for (int k0 = 0; k0 < 128; k0 += 32) {
#pragma unroll
    for (int l = 0; l < 2; l++) {
      const int e = tid + l * 256;
      const int row = e >> 3, c4 = (e & 7) << 2;
      const float4 va = *(const float4*)&q[(rb + row) * 1024 + m * 128 + k0 + c4];
      As[c4 + 0][row] = va.x; As[c4 + 1][row] = va.y;
      As[c4 + 2][row] = va.z; As[c4 + 3][row] = va.w;
      const float4 vb = *(const float4*)&kcb[(m * 256 + cb0 + row) * 128 + k0 + c4];
      Bs[c4 + 0][row] = vb.x; Bs[c4 + 1][row] = vb.y;
      Bs[c4 + 2][row] = vb.z; Bs[c4 + 3][row] = vb.w;
    }
    __syncthreads();
#pragma unroll
    for (int kk = 0; kk < 32; kk++) {
      const float4 a = *(const float4*)&As[kk][ty << 2];
      const float4 b = *(const float4*)&Bs[kk][tx << 2];
      const float ar[4] = {a.x, a.y, a.z, a.w};
      const float br[4] = {b.x, b.y, b.z, b.w};
#pragma unroll
      for (int r = 0; r < 4; r++)
#pragma unroll
        for (int c = 0; c < 4; c++)
          acc[r][c] = fmaf(ar[r], br[c], acc[r][c]);
    }
    __syncthreads();
  }
#pragma unroll
  for (int r = 0; r < 4; r++) {
    const int row = rb + (ty << 2) + r;
    const float qv = qsq[row * 8 + m];
    float4 v;
    const int col = cb0 + (tx << 2);
    v.x = qv + csq[m * 256 + col + 0] - 2.0f * acc[r][0];
    v.y = qv + csq[m * 256 + col + 1] - 2.0f * acc[r][1];
    v.z = qv + csq[m * 256 + col + 2] - 2.0f * acc[r][2];
    v.w = qv + csq[m * 256 + col + 3] - 2.0f * acc[r][3];
    *(float4*)&lut[row * 2048 + m * 256 + col] = v;
  }
}

// ---------------- Kernel 4a: ADC scan, 32 single-bank replicas (128KB dyn LDS) ----
// Replica r lives ENTIRELY in bank r: entry e at byte (e>>1)*128 + r*4 + (e&1)*2.
// Lane l uses r=l&31 -> 2 lanes/bank, distinct dwords = conflict-free (m136).
// Init staged through 4KB temp so both read (broadcast) and 32-way replication
// write (bank=r per lane) are conflict-free.
extern __shared__ char dyn_lds[];

__launch_bounds__(512)
__global__ void scan32_kernel(const float* __restrict__ lut,
                              const uint4* __restrict__ poffs,
                              unsigned* __restrict__ cand_d,
                              unsigned short* __restrict__ cand_n) {
  char* rep = dyn_lds;                                  // 131072 B
  unsigned* repw = (unsigned*)dyn_lds;
  unsigned* temp = (unsigned*)(dyn_lds + 131072);       // 1024 dwords
  const int tid = threadIdx.x;
  const int b = blockIdx.x;

  // quantize: wave w <-> segment m=w; center by segment mean (top-k/softmax
  // invariant), scale 64, clamp +-32000
  const float4 v4 = *(const float4*)&lut[b * 2048 + tid * 4];
  float s4 = v4.x + v4.y + v4.z + v4.w;
#pragma unroll
  for (int off = 32; off > 0; off >>= 1) s4 += __shfl_xor(s4, off);
  const float mean = s4 * (1.0f / 256.0f);
  const float vals[4] = {v4.x, v4.y, v4.z, v4.w};
  int qv[4];
#pragma unroll
  for (int k2 = 0; k2 < 4; k2++) {
    float f = (vals[k2] - mean) * 64.0f;
    f = fmaxf(fminf(f, 32000.0f), -32000.0f);
    qv[k2] = (int)rintf(f);
  }
  temp[tid * 2]     = ((unsigned)qv[0] & 0xFFFFu) | ((unsigned)qv[1] << 16);
  temp[tid * 2 + 1] = ((unsigned)qv[2] & 0xFFFFu) | ((unsigned)qv[3] << 16);
  __syncthreads();

  const int r = tid & 31;
  {
    const int chunk = tid >> 5;  // 16 chunks x 64 dwords
    for (int j = 0; j < 64; j += 2) {
      const int idx = chunk * 64 + j;
      const unsigned long long tv = *(const unsigned long long*)&temp[idx];
      repw[idx * 32 + r] = (unsigned)tv;
      repw[(idx + 1) * 32 + r] = (unsigned)(tv >> 32);
    }
  }
  __syncthreads();

  const int rb0 = r * 4;            // byte base for m=0..3 (h has (m&3)<<14)
  const int rb1 = r * 4 + 65536;    // byte base for m=4..7
  int d0 = 0x7FFFFFFF, d1 = 0x7FFFFFFF, d2 = 0x7FFFFFFF, d3 = 0x7FFFFFFF;
  int i0 = 0, i1 = 0, i2 = 0, i3 = 0;

  uint4 oc = poffs[tid];
  uint4 nc = poffs[tid + 512];
  for (int it = 0; it < 128; it++) {
    const int n = tid + (it << 9);
    uint4 nn2 = nc;
    if (it < 126) nn2 = poffs[n + 1024];  // depth-2 prefetch
    int s;
    s  = *(const short*)(rep + rb0 + (oc.x & 0xFFFFu));
    s += *(const short*)(rep + rb0 + (oc.x >> 16));
    s += *(const short*)(rep + rb0 + (oc.y & 0xFFFFu));
    s += *(const short*)(rep + rb0 + (oc.y >> 16));
    s += *(const short*)(rep + rb1 + (oc.z & 0xFFFFu));
    s += *(const short*)(rep + rb1 + (oc.z >> 16));
    s += *(const short*)(rep + rb1 + (oc.w & 0xFFFFu));
    s += *(const short*)(rep + rb1 + (oc.w >> 16));
    if (s < d3) {
      if (s < d1) {
        if (s < d0) { d3 = d2; i3 = i2; d2 = d1; i2 = i1; d1 = d0; i1 = i0; d0 = s; i0 = n; }
        else        { d3 = d2; i3 = i2; d2 = d1; i2 = i1; d1 = s; i1 = n; }
      } else {
        if (s < d2) { d3 = d2; i3 = i2; d2 = s; i2 = n; }
        else        { d3 = s; i3 = n; }
      }
    }
    oc = nc; nc = nn2;
  }

  const int base = b * 2048 + tid * 4;
  const uint4 dv = make_uint4((unsigned)(d0 + 0x40000000), (unsigned)(d1 + 0x40000000),
                              (unsigned)(d2 + 0x40000000), (unsigned)(d3 + 0x40000000));
  *(uint4*)&cand_d[base] = dv;
  const unsigned ni01 = (unsigned)i0 | ((unsigned)i1 << 16);
  const unsigned ni23 = (unsigned)i2 | ((unsigned)i3 << 16);
  *(uint2*)&cand_n[base] = make_uint2(ni01, ni23);
}

// ---------------- Kernel 4b: fallback 64KB scan (round-2 kernel, verified) ----
__launch_bounds__(512)
__global__ void scan16_kernel(const float* __restrict__ lut,
                              const unsigned long long* __restrict__ pcodes,
                              unsigned* __restrict__ cand_d,
                              unsigned short* __restrict__ cand_n) {
  __shared__ short sRep[32768];
  const int tid = threadIdx.x;
  const int b = blockIdx.x;

  const float4 v4 = *(const float4*)&lut[b * 2048 + tid * 4];
  float s4 = v4.x + v4.y + v4.z + v4.w;
#pragma unroll
  for (int off = 32; off > 0; off >>= 1) s4 += __shfl_xor(s4, off);
  const float mean = s4 * (1.0f / 256.0f);

  const float vals[4] = {v4.x, v4.y, v4.z, v4.w};
#pragma unroll
  for (int k2 = 0; k2 < 4; k2++) {
    float f = (vals[k2] - mean) * 64.0f;
    f = fmaxf(fminf(f, 32000.0f), -32000.0f);
    const int iv = (int)rintf(f);
    const unsigned hw = (unsigned)(unsigned short)iv;
    const unsigned wrd = hw | (hw << 16);
    const uint4 wv = make_uint4(wrd, wrd, wrd, wrd);
    const int e = tid * 4 + k2;
    *(uint4*)&((unsigned*)sRep)[e * 8] = wv;
    *(uint4*)&((unsigned*)sRep)[e * 8 + 4] = wv;
  }
  __syncthreads();

  const int r = tid & 15;
  int d0 = 0x7FFFFFFF, d1 = 0x7FFFFFFF, d2 = 0x7FFFFFFF, d3 = 0x7FFFFFFF;
  int i0 = 0, i1 = 0, i2 = 0, i3 = 0;

  unsigned long long c8 = pcodes[tid];
  for (int it = 0; it < 128; it++) {
    const int n = tid + (it << 9);
    unsigned long long nxt = 0ull;
    if (it < 127) nxt = pcodes[n + 512];
    const unsigned lo = (unsigned)c8;
    const unsigned hi = (unsigned)(c8 >> 32);
    int s;
    s  = sRep[(((lo      ) & 255u) << 4) + r        ];
    s += sRep[(((lo >>  8) & 255u) << 4) + r +  4096];
    s += sRep[(((lo >> 16) & 255u) << 4) + r +  8192];
    s += sRep[(((lo >> 24)       ) << 4) + r + 12288];
    s += sRep[(((hi      ) & 255u) << 4) + r + 16384];
    s += sRep[(((hi >>  8) & 255u) << 4) + r + 20480];
    s += sRep[(((hi >> 16) & 255u) << 4) + r + 24576];
    s += sRep[(((hi >> 24)       ) << 4) + r + 28672];
    if (s < d3) {
      if (s < d1) {
        if (s < d0) { d3 = d2; i3 = i2; d2 = d1; i2 = i1; d1 = d0; i1 = i0; d0 = s; i0 = n; }
        else        { d3 = d2; i3 = i2; d2 = d1; i2 = i1; d1 = s; i1 = n; }
      } else {
        if (s < d2) { d3 = d2; i3 = i2; d2 = s; i2 = n; }
        else        { d3 = s; i3 = n; }
      }
    }
    c8 = nxt;
  }

  const int base = b * 2048 + tid * 4;
  const uint4 dv = make_uint4((unsigned)(d0 + 0x40000000), (unsigned)(d1 + 0x40000000),
                              (unsigned)(d2 + 0x40000000), (unsigned)(d3 + 0x40000000));
  *(uint4*)&cand_d[base] = dv;
  const unsigned ni01 = (unsigned)i0 | ((unsigned)i1 << 16);
  const unsigned ni23 = (unsigned)i2 | ((unsigned)i3 << 16);
  *(uint2*)&cand_n[base] = make_uint2(ni01, ni23);
}

// ---------------- Kernel 5: select top-64 + softmax + value gather ----------
__launch_bounds__(256)
__global__ void select_kernel(const unsigned* __restrict__ cand_d,
                              const unsigned short* __restrict__ cand_n,
                              const int* __restrict__ value_codes,
                              const float* __restrict__ vcb,
                              const float* __restrict__ bias,
                              float* __restrict__ out) {
  __shared__ unsigned long long clist[1024];
  __shared__ unsigned sred[256];
  __shared__ int svc[64][8];
  __shared__ float sw[64];
  __shared__ int sidx[64];
  __shared__ int scnt;
  __shared__ unsigned sU;

  const int tid = threadIdx.x;
  const int b = blockIdx.x;

  const uint4 a0 = *(const uint4*)&cand_d[b * 2048 + tid * 8];
  const uint4 a1 = *(const uint4*)&cand_d[b * 2048 + tid * 8 + 4];
  const uint4 nn = *(const uint4*)&cand_n[b * 2048 + tid * 8];
  unsigned dk[8] = {a0.x, a0.y, a0.z, a0.w, a1.x, a1.y, a1.z, a1.w};
  unsigned ni[8] = {nn.x & 0xFFFFu, nn.x >> 16, nn.y & 0xFFFFu, nn.y >> 16,
                    nn.z & 0xFFFFu, nn.z >> 16, nn.w & 0xFFFFu, nn.w >> 16};

  if (tid == 0) scnt = 0;
  sred[tid] = (a0.x < a1.x) ? a0.x : a1.x;
  __syncthreads();
  if (tid < 64) {
    unsigned g = sred[tid * 4];
#pragma unroll
    for (int j = 1; j < 4; j++) { const unsigned v = sred[tid * 4 + j]; if (v < g) g = v; }
#pragma unroll
    for (int off = 32; off > 0; off >>= 1) {
      const unsigned o = __shfl_xor(g, off);
      if (o > g) g = o;
    }
    if (tid == 0) sU = g;
  }
  __syncthreads();
  const unsigned U = sU;

#pragma unroll
  for (int j = 0; j < 8; j++) {
    if (dk[j] <= U) {
      const int p = atomicAdd(&scnt, 1);
      if (p < 1024) clist[p] = ((unsigned long long)dk[j] << 32) | ni[j];
    }
  }
  __syncthreads();
  const int cnt = min(scnt, 1024);
  const int SZ = (cnt <= 256) ? 256 : ((cnt <= 512) ? 512 : 1024);
  for (int i = tid; i < SZ; i += 256)
    if (i >= cnt) clist[i] = ~0ull;
  __syncthreads();

  for (int k = 2; k <= SZ; k <<= 1) {
    for (int j = k >> 1; j > 0; j >>= 1) {
      for (int i = tid; i < SZ; i += 256) {
        const int ix = i ^ j;
        if (ix > i) {
          const unsigned long long a = clist[i], c = clist[ix];
          const bool up = ((i & k) == 0);
          if ((a > c) == up) { clist[i] = c; clist[ix] = a; }
        }
      }
      __syncthreads();
    }
  }

  if (tid < 64) {
    const unsigned long long e = clist[tid];
    const int d_int = (int)((unsigned)(e >> 32)) - 0x40000000;
    const float d = (float)d_int * (1.0f / 64.0f);
    const int idx = (int)(e & 0xFFFFFFFFu);
    const float dmin = __shfl(d, 0);
    const float w = __expf(dmin - d);
    float ws = w;
#pragma unroll
    for (int off = 32; off > 0; off >>= 1) ws += __shfl_xor(ws, off);
    sw[tid] = w / ws;
    sidx[tid] = idx;
  }
  __syncthreads();

  for (int i = tid; i < 512; i += 256)
    svc[i >> 3][i & 7] = value_codes[sidx[i >> 3] * 8 + (i & 7)];
  __syncthreads();

  const int c0 = tid << 3;
  const int mv = c0 >> 8;
  const int off = c0 & 255;
  float4 acc0 = *(const float4*)&bias[c0];
  float4 acc1 = *(const float4*)&bias[c0 + 4];
  const float* vbase = vcb + mv * 65536 + off;
  for (int k = 0; k < 64; k++) {
    const float w = sw[k];
    const float* vp = vbase + svc[k][mv] * 256;
    const float4 v0 = *(const float4*)vp;
    const float4 v1 = *(const float4*)(vp + 4);
    acc0.x = fmaf(w, v0.x, acc0.x); acc0.y = fmaf(w, v0.y, acc0.y);
    acc0.z = fmaf(w, v0.z, acc0.z); acc0.w = fmaf(w, v0.w, acc0.w);
    acc1.x = fmaf(w, v1.x, acc1.x); acc1.y = fmaf(w, v1.y, acc1.y);
    acc1.z = fmaf(w, v1.z, acc1.z); acc1.w = fmaf(w, v1.w, acc1.w);
  }
  *(float4*)&out[b * 2048 + c0] = acc0;
  *(float4*)&out[b * 2048 + c0 + 4] = acc1;
}

// ---------------- launch ----------------
extern "C" void kernel_launch(void* const* d_in, const int* in_sizes, int n_in,
                              void* d_out, int out_size, void* d_ws, size_t ws_size,
                              hipStream_t stream) {
  const float* x    = (const float*)d_in[0];
  const float* W    = (const float*)d_in[1];
  const float* kcb  = (const float*)d_in[2];
  const float* vcb  = (const float*)d_in[3];
  const float* bias = (const float*)d_in[4];
  const int* key_codes   = (const int*)d_in[5];
  const int* value_codes = (const int*)d_in[6];
  float* out = (float*)d_out;

  // ws layout (~25.6 MB): q 4MB | lut 8MB | qsq 32KB | csq 8KB | pcodes 512KB
  //                       | poffs 1MB | cand_d 8MB | cand_n 4MB
  float* q   = (float*)d_ws;
  float* lut = q + 1048576;
  float* qsq = lut + 2097152;
  float* csq = qsq + 8192;
  unsigned long long* pcodes = (unsigned long long*)(csq + 2048);
  uint4* poffs = (uint4*)(pcodes + 65536);
  unsigned* cand_d = (unsigned*)(poffs + 65536);
  unsigned short* cand_n = (unsigned short*)(cand_d + 2097152);

  hipLaunchKernelGGL(gemm_q_kernel, dim3(16, 16), dim3(256), 0, stream, x, W, q);
  hipLaunchKernelGGL(prep_kernel, dim3(256), dim3(256), 0, stream,
                     q, kcb, key_codes, qsq, csq, pcodes, poffs);
  hipLaunchKernelGGL(lut_kernel, dim3(4, 16, 8), dim3(256), 0, stream,
                     q, kcb, qsq, csq, lut);

  // 132 KB dynamic LDS (gfx950 GROUP segment = 160 KiB). Deterministic
  // host-side attribute set every call; fall back to 64KB kernel on failure.
  const hipError_t attr_rc = hipFuncSetAttribute(
      (const void*)scan32_kernel, hipFuncAttributeMaxDynamicSharedMemorySize, 135168);
  if (attr_rc == hipSuccess) {
    hipLaunchKernelGGL(scan32_kernel, dim3(1024), dim3(512), 135168, stream,
                       lut, poffs, cand_d, cand_n);
  } else {
    hipLaunchKernelGGL(scan16_kernel, dim3(1024), dim3(512), 0, stream,
                       lut, pcodes, cand_d, cand_n);
  }

  hipLaunchKernelGGL(select_kernel, dim3(1024), dim3(256), 0, stream,
                     cand_d, cand_n, value_codes, vcb, bias, out);
}

// Round 4
// 284.610 us; speedup vs baseline: 1.0593x; 1.0593x over previous
//
#include <hip/hip_runtime.h>

#define N_ITEMS 65536

// ---------------- Kernel 0: zero q (ws is poisoned 0xAA before every call) ----
__launch_bounds__(256)
__global__ void zero_q_kernel(float4* __restrict__ q4) {
  q4[blockIdx.x * 256 + threadIdx.x] = make_float4(0.f, 0.f, 0.f, 0.f);
}

// ---------------- Kernel 1: q = x @ W  (1024x1024x1024, fp32, K-split x4) ----
// grid (16,16,4): z = K-chunk of 256. 1024 blocks -> 4/CU, 16 waves/CU
// (vs 1 wave/SIMD unsplit). fp32 accumulate via HW atomic (order noise ~1e-5,
// far below quantizer step). 64x64 tile, BK=32, register double-buffered.
__launch_bounds__(256)
__global__ void gemm_q_kernel(const float* __restrict__ A,
                              const float* __restrict__ W,
                              float* __restrict__ C) {
  __shared__ float As[32][68];
  __shared__ float Bs[32][68];
  const int tid = threadIdx.x;
  const int tx = tid & 15, ty = tid >> 4;
  const int rb = blockIdx.y * 64, cb = blockIdx.x * 64;
  const int kz = blockIdx.z * 256;
  const int r0 = tid >> 3, c4 = (tid & 7) << 2;
  const int r1 = r0 + 32;
  const int kk0 = tid >> 4, c4b = (tid & 15) << 2;
  const int kk1 = kk0 + 16;

  float4 va0 = *(const float4*)&A[(rb + r0) * 1024 + kz + c4];
  float4 va1 = *(const float4*)&A[(rb + r1) * 1024 + kz + c4];
  float4 vb0 = *(const float4*)&W[(kz + kk0) * 1024 + cb + c4b];
  float4 vb1 = *(const float4*)&W[(kz + kk1) * 1024 + cb + c4b];

  float acc[4][4] = {};
  for (int k0 = kz; k0 < kz + 256; k0 += 32) {
    As[c4 + 0][r0] = va0.x; As[c4 + 1][r0] = va0.y;
    As[c4 + 2][r0] = va0.z; As[c4 + 3][r0] = va0.w;
    As[c4 + 0][r1] = va1.x; As[c4 + 1][r1] = va1.y;
    As[c4 + 2][r1] = va1.z; As[c4 + 3][r1] = va1.w;
    *(float4*)&Bs[kk0][c4b] = vb0;
    *(float4*)&Bs[kk1][c4b] = vb1;
    __syncthreads();
    if (k0 + 32 < kz + 256) {
      va0 = *(const float4*)&A[(rb + r0) * 1024 + k0 + 32 + c4];
      va1 = *(const float4*)&A[(rb + r1) * 1024 + k0 + 32 + c4];
      vb0 = *(const float4*)&W[(k0 + 32 + kk0) * 1024 + cb + c4b];
      vb1 = *(const float4*)&W[(k0 + 32 + kk1) * 1024 + cb + c4b];
    }
#pragma unroll
    for (int kk = 0; kk < 32; kk++) {
      const float4 a = *(const float4*)&As[kk][ty << 2];
      const float4 b = *(const float4*)&Bs[kk][tx << 2];
      const float ar[4] = {a.x, a.y, a.z, a.w};
      const float br[4] = {b.x, b.y, b.z, b.w};
#pragma unroll
      for (int r = 0; r < 4; r++)
#pragma unroll
        for (int c = 0; c < 4; c++)
          acc[r][c] = fmaf(ar[r], br[c], acc[r][c]);
    }
    __syncthreads();
  }
#pragma unroll
  for (int r = 0; r < 4; r++)
#pragma unroll
    for (int c = 0; c < 4; c++)
      unsafeAtomicAdd(&C[(rb + (ty << 2) + r) * 1024 + cb + (tx << 2) + c], acc[r][c]);
}

// ---------------- Kernel 2: prep — q_sq, c_sq, packed codes + LDS offsets ----
__launch_bounds__(256)
__global__ void prep_kernel(const float* __restrict__ q,
                            const float* __restrict__ kcb,
                            const int* __restrict__ key_codes,
                            float* __restrict__ qsq,
                            float* __restrict__ csq,
                            unsigned long long* __restrict__ pcodes,
                            uint4* __restrict__ poffs) {
  const int gid = blockIdx.x * 256 + threadIdx.x;
  if (gid < N_ITEMS) {
    unsigned long long p = 0ull;
    unsigned h[8];
#pragma unroll
    for (int j = 0; j < 8; j++) {
      const unsigned c = (unsigned)key_codes[gid * 8 + j] & 255u;
      p |= (unsigned long long)c << (8 * j);
      h[j] = ((unsigned)(j & 3) << 14) | ((c >> 1) << 7) | ((c & 1u) << 1);
    }
    pcodes[gid] = p;
    poffs[gid] = make_uint4(h[0] | (h[1] << 16), h[2] | (h[3] << 16),
                            h[4] | (h[5] << 16), h[6] | (h[7] << 16));
  }
  if (gid < 8192) {
    const float* p = &q[(gid >> 3) * 1024 + (gid & 7) * 128];
    float s = 0.f;
#pragma unroll 4
    for (int k = 0; k < 128; k++) s = fmaf(p[k], p[k], s);
    qsq[gid] = s;
  }
  if (gid < 2048) {
    const float* p = &kcb[gid * 128];
    float s = 0.f;
#pragma unroll 4
    for (int k = 0; k < 128; k++) s = fmaf(p[k], p[k], s);
    csq[gid] = s;
  }
}

// ---------------- Kernel 3: lut[b][m*256+c] = qsq + csq - 2*qs.cb ----------------
__launch_bounds__(256)
__global__ void lut_kernel(const float* __restrict__ q,
                           const float* __restrict__ kcb,
                           const float* __restrict__ qsq,
                           const float* __restrict__ csq,
                           float* __restrict__ lut) {
  __shared__ float As[32][68];
  __shared__ float Bs[32][68];
  const int tid = threadIdx.x;
  const int tx = tid & 15, ty = tid >> 4;
  const int m = blockIdx.z;
  const int rb = blockIdx.y * 64;
  const int cb0 = blockIdx.x * 64;
  float acc[4][4] = {};
  for (int k0 = 0; k0 < 128; k0 += 32) {
#pragma unroll
    for (int l = 0; l < 2; l++) {
      const int e = tid + l * 256;
      const int row = e >> 3, c4 = (e & 7) << 2;
      const float4 va = *(const float4*)&q[(rb + row) * 1024 + m * 128 + k0 + c4];
      As[c4 + 0][row] = va.x; As[c4 + 1][row] = va.y;
      As[c4 + 2][row] = va.z; As[c4 + 3][row] = va.w;
      const float4 vb = *(const float4*)&kcb[(m * 256 + cb0 + row) * 128 + k0 + c4];
      Bs[c4 + 0][row] = vb.x; Bs[c4 + 1][row] = vb.y;
      Bs[c4 + 2][row] = vb.z; Bs[c4 + 3][row] = vb.w;
    }
    __syncthreads();
#pragma unroll
    for (int kk = 0; kk < 32; kk++) {
      const float4 a = *(const float4*)&As[kk][ty << 2];
      const float4 b = *(const float4*)&Bs[kk][tx << 2];
      const float ar[4] = {a.x, a.y, a.z, a.w};
      const float br[4] = {b.x, b.y, b.z, b.w};
#pragma unroll
      for (int r = 0; r < 4; r++)
#pragma unroll
        for (int c = 0; c < 4; c++)
          acc[r][c] = fmaf(ar[r], br[c], acc[r][c]);
    }
    __syncthreads();
  }
#pragma unroll
  for (int r = 0; r < 4; r++) {
    const int row = rb + (ty << 2) + r;
    const float qv = qsq[row * 8 + m];
    float4 v;
    const int col = cb0 + (tx << 2);
    v.x = qv + csq[m * 256 + col + 0] - 2.0f * acc[r][0];
    v.y = qv + csq[m * 256 + col + 1] - 2.0f * acc[r][1];
    v.z = qv + csq[m * 256 + col + 2] - 2.0f * acc[r][2];
    v.w = qv + csq[m * 256 + col + 3] - 2.0f * acc[r][3];
    *(float4*)&lut[row * 2048 + m * 256 + col] = v;
  }
}

// ---------------- Kernel 4a: ADC scan, 32 single-bank replicas, 1024 thr ----
// 128KB table (replica r entirely in bank r; lane uses r=lane&31 -> 2
// lanes/bank = conflict-free, verified: SQ_LDS_BANK_CONFLICT 3.6e7 -> 3.3e4).
// LDS caps us at 1 block/CU, so block = 1024 threads (16 waves, 4/SIMD) for
// latency hiding; each lane scans 64 items, keeps top-2.
extern __shared__ char dyn_lds[];

__launch_bounds__(1024)
__global__ void scan32_kernel(const float* __restrict__ lut,
                              const uint4* __restrict__ poffs,
                              unsigned* __restrict__ cand_d,
                              unsigned short* __restrict__ cand_n) {
  char* rep = dyn_lds;                                  // 131072 B
  unsigned* repw = (unsigned*)dyn_lds;
  unsigned* temp = (unsigned*)(dyn_lds + 131072);       // 1024 dwords
  const int tid = threadIdx.x;
  const int b = blockIdx.x;

  // quantize: threads 0..511, wave w <-> segment m=w; center by segment mean
  if (tid < 512) {
    const float4 v4 = *(const float4*)&lut[b * 2048 + tid * 4];
    float s4 = v4.x + v4.y + v4.z + v4.w;
#pragma unroll
    for (int off = 32; off > 0; off >>= 1) s4 += __shfl_xor(s4, off);
    const float mean = s4 * (1.0f / 256.0f);
    const float vals[4] = {v4.x, v4.y, v4.z, v4.w};
    int qv[4];
#pragma unroll
    for (int k2 = 0; k2 < 4; k2++) {
      float f = (vals[k2] - mean) * 64.0f;
      f = fmaxf(fminf(f, 32000.0f), -32000.0f);
      qv[k2] = (int)rintf(f);
    }
    temp[tid * 2]     = ((unsigned)qv[0] & 0xFFFFu) | ((unsigned)qv[1] << 16);
    temp[tid * 2 + 1] = ((unsigned)qv[2] & 0xFFFFu) | ((unsigned)qv[3] << 16);
  }
  __syncthreads();

  const int r = tid & 31;
  {
    const int chunk = tid >> 5;  // 32 chunks x 32 dwords
    for (int j = 0; j < 32; j += 2) {
      const int idx = chunk * 32 + j;
      const unsigned long long tv = *(const unsigned long long*)&temp[idx];
      repw[idx * 32 + r] = (unsigned)tv;
      repw[(idx + 1) * 32 + r] = (unsigned)(tv >> 32);
    }
  }
  __syncthreads();

  const int rb0 = r * 4;            // byte base m=0..3
  const int rb1 = r * 4 + 65536;    // byte base m=4..7
  int d0 = 0x7FFFFFFF, d1 = 0x7FFFFFFF;
  int i0 = 0, i1 = 0;

  uint4 oc = poffs[tid];
  uint4 nc = poffs[tid + 1024];
  for (int it = 0; it < 64; it++) {
    const int n = tid + (it << 10);
    uint4 nn2 = nc;
    if (it < 62) nn2 = poffs[n + 2048];  // depth-2 prefetch
    int s;
    s  = *(const short*)(rep + rb0 + (oc.x & 0xFFFFu));
    s += *(const short*)(rep + rb0 + (oc.x >> 16));
    s += *(const short*)(rep + rb0 + (oc.y & 0xFFFFu));
    s += *(const short*)(rep + rb0 + (oc.y >> 16));
    s += *(const short*)(rep + rb1 + (oc.z & 0xFFFFu));
    s += *(const short*)(rep + rb1 + (oc.z >> 16));
    s += *(const short*)(rep + rb1 + (oc.w & 0xFFFFu));
    s += *(const short*)(rep + rb1 + (oc.w >> 16));
    if (s < d1) {
      if (s < d0) { d1 = d0; i1 = i0; d0 = s; i0 = n; }
      else        { d1 = s; i1 = n; }
    }
    oc = nc; nc = nn2;
  }

  const int base = b * 2048 + tid * 2;
  *(uint2*)&cand_d[base] = make_uint2((unsigned)(d0 + 0x40000000),
                                      (unsigned)(d1 + 0x40000000));
  *(unsigned*)&cand_n[base] = (unsigned)i0 | ((unsigned)i1 << 16);
}

// ---------------- Kernel 4b: fallback 64KB scan (512 thr, top-4/lane) --------
__launch_bounds__(512)
__global__ void scan16_kernel(const float* __restrict__ lut,
                              const unsigned long long* __restrict__ pcodes,
                              unsigned* __restrict__ cand_d,
                              unsigned short* __restrict__ cand_n) {
  __shared__ short sRep[32768];
  const int tid = threadIdx.x;
  const int b = blockIdx.x;

  const float4 v4 = *(const float4*)&lut[b * 2048 + tid * 4];
  float s4 = v4.x + v4.y + v4.z + v4.w;
#pragma unroll
  for (int off = 32; off > 0; off >>= 1) s4 += __shfl_xor(s4, off);
  const float mean = s4 * (1.0f / 256.0f);

  const float vals[4] = {v4.x, v4.y, v4.z, v4.w};
#pragma unroll
  for (int k2 = 0; k2 < 4; k2++) {
    float f = (vals[k2] - mean) * 64.0f;
    f = fmaxf(fminf(f, 32000.0f), -32000.0f);
    const int iv = (int)rintf(f);
    const unsigned hw = (unsigned)(unsigned short)iv;
    const unsigned wrd = hw | (hw << 16);
    const uint4 wv = make_uint4(wrd, wrd, wrd, wrd);
    const int e = tid * 4 + k2;
    *(uint4*)&((unsigned*)sRep)[e * 8] = wv;
    *(uint4*)&((unsigned*)sRep)[e * 8 + 4] = wv;
  }
  __syncthreads();

  const int r = tid & 15;
  int d0 = 0x7FFFFFFF, d1 = 0x7FFFFFFF, d2 = 0x7FFFFFFF, d3 = 0x7FFFFFFF;
  int i0 = 0, i1 = 0, i2 = 0, i3 = 0;

  unsigned long long c8 = pcodes[tid];
  for (int it = 0; it < 128; it++) {
    const int n = tid + (it << 9);
    unsigned long long nxt = 0ull;
    if (it < 127) nxt = pcodes[n + 512];
    const unsigned lo = (unsigned)c8;
    const unsigned hi = (unsigned)(c8 >> 32);
    int s;
    s  = sRep[(((lo      ) & 255u) << 4) + r        ];
    s += sRep[(((lo >>  8) & 255u) << 4) + r +  4096];
    s += sRep[(((lo >> 16) & 255u) << 4) + r +  8192];
    s += sRep[(((lo >> 24)       ) << 4) + r + 12288];
    s += sRep[(((hi      ) & 255u) << 4) + r + 16384];
    s += sRep[(((hi >>  8) & 255u) << 4) + r + 20480];
    s += sRep[(((hi >> 16) & 255u) << 4) + r + 24576];
    s += sRep[(((hi >> 24)       ) << 4) + r + 28672];
    if (s < d3) {
      if (s < d1) {
        if (s < d0) { d3 = d2; i3 = i2; d2 = d1; i2 = i1; d1 = d0; i1 = i0; d0 = s; i0 = n; }
        else        { d3 = d2; i3 = i2; d2 = d1; i2 = i1; d1 = s; i1 = n; }
      } else {
        if (s < d2) { d3 = d2; i3 = i2; d2 = s; i2 = n; }
        else        { d3 = s; i3 = n; }
      }
    }
    c8 = nxt;
  }

  const int base = b * 2048 + tid * 4;
  const uint4 dv = make_uint4((unsigned)(d0 + 0x40000000), (unsigned)(d1 + 0x40000000),
                              (unsigned)(d2 + 0x40000000), (unsigned)(d3 + 0x40000000));
  *(uint4*)&cand_d[base] = dv;
  const unsigned ni01 = (unsigned)i0 | ((unsigned)i1 << 16);
  const unsigned ni23 = (unsigned)i2 | ((unsigned)i3 << 16);
  *(uint2*)&cand_n[base] = make_uint2(ni01, ni23);
}

// ---------------- Kernel 5: select top-64 + softmax + value gather ----------
// U = max over 64 disjoint lane-groups of group-min: sred = min over ALL of a
// thread's 8 entries (equals min over its lanes' bests for BOTH scan layouts).
__launch_bounds__(256)
__global__ void select_kernel(const unsigned* __restrict__ cand_d,
                              const unsigned short* __restrict__ cand_n,
                              const int* __restrict__ value_codes,
                              const float* __restrict__ vcb,
                              const float* __restrict__ bias,
                              float* __restrict__ out) {
  __shared__ unsigned long long clist[1024];
  __shared__ unsigned sred[256];
  __shared__ int svc[64][8];
  __shared__ float sw[64];
  __shared__ int sidx[64];
  __shared__ int scnt;
  __shared__ unsigned sU;

  const int tid = threadIdx.x;
  const int b = blockIdx.x;

  const uint4 a0 = *(const uint4*)&cand_d[b * 2048 + tid * 8];
  const uint4 a1 = *(const uint4*)&cand_d[b * 2048 + tid * 8 + 4];
  const uint4 nn = *(const uint4*)&cand_n[b * 2048 + tid * 8];
  unsigned dk[8] = {a0.x, a0.y, a0.z, a0.w, a1.x, a1.y, a1.z, a1.w};
  unsigned ni[8] = {nn.x & 0xFFFFu, nn.x >> 16, nn.y & 0xFFFFu, nn.y >> 16,
                    nn.z & 0xFFFFu, nn.z >> 16, nn.w & 0xFFFFu, nn.w >> 16};

  if (tid == 0) scnt = 0;
  unsigned mn = dk[0];
#pragma unroll
  for (int j = 1; j < 8; j++) mn = (dk[j] < mn) ? dk[j] : mn;
  sred[tid] = mn;
  __syncthreads();
  if (tid < 64) {
    unsigned g = sred[tid * 4];
#pragma unroll
    for (int j = 1; j < 4; j++) { const unsigned v = sred[tid * 4 + j]; if (v < g) g = v; }
#pragma unroll
    for (int off = 32; off > 0; off >>= 1) {
      const unsigned o = __shfl_xor(g, off);
      if (o > g) g = o;
    }
    if (tid == 0) sU = g;
  }
  __syncthreads();
  const unsigned U = sU;

  // ballot compaction: 8 wave-wide passes, 1 LDS atomic per wave per pass
  const int lane = tid & 63;
  const unsigned long long lm = (1ull << lane) - 1ull;
#pragma unroll
  for (int j = 0; j < 8; j++) {
    const bool pred = dk[j] <= U;
    const unsigned long long mask = __ballot(pred);
    int base = 0;
    if (lane == 0 && mask) base = atomicAdd(&scnt, __popcll(mask));
    base = __shfl(base, 0);
    if (pred) {
      const int pos = base + __popcll(mask & lm);
      if (pos < 1024) clist[pos] = ((unsigned long long)dk[j] << 32) | ni[j];
    }
  }
  __syncthreads();
  const int cnt = min(scnt, 1024);
  const int SZ = (cnt <= 256) ? 256 : ((cnt <= 512) ? 512 : 1024);
  for (int i = tid; i < SZ; i += 256)
    if (i >= cnt) clist[i] = ~0ull;
  __syncthreads();

  for (int k = 2; k <= SZ; k <<= 1) {
    for (int j = k >> 1; j > 0; j >>= 1) {
      for (int i = tid; i < SZ; i += 256) {
        const int ix = i ^ j;
        if (ix > i) {
          const unsigned long long a = clist[i], c = clist[ix];
          const bool up = ((i & k) == 0);
          if ((a > c) == up) { clist[i] = c; clist[ix] = a; }
        }
      }
      __syncthreads();
    }
  }

  if (tid < 64) {
    const unsigned long long e = clist[tid];
    const int d_int = (int)((unsigned)(e >> 32)) - 0x40000000;
    const float d = (float)d_int * (1.0f / 64.0f);
    const int idx = (int)(e & 0xFFFFFFFFu);
    const float dmin = __shfl(d, 0);
    const float w = __expf(dmin - d);
    float ws = w;
#pragma unroll
    for (int off = 32; off > 0; off >>= 1) ws += __shfl_xor(ws, off);
    sw[tid] = w / ws;
    sidx[tid] = idx;
  }
  __syncthreads();

  for (int i = tid; i < 512; i += 256)
    svc[i >> 3][i & 7] = value_codes[sidx[i >> 3] * 8 + (i & 7)];
  __syncthreads();

  const int c0 = tid << 3;
  const int mv = c0 >> 8;
  const int off = c0 & 255;
  float4 acc0 = *(const float4*)&bias[c0];
  float4 acc1 = *(const float4*)&bias[c0 + 4];
  const float* vbase = vcb + mv * 65536 + off;
  for (int k = 0; k < 64; k++) {
    const float w = sw[k];
    const float* vp = vbase + svc[k][mv] * 256;
    const float4 v0 = *(const float4*)vp;
    const float4 v1 = *(const float4*)(vp + 4);
    acc0.x = fmaf(w, v0.x, acc0.x); acc0.y = fmaf(w, v0.y, acc0.y);
    acc0.z = fmaf(w, v0.z, acc0.z); acc0.w = fmaf(w, v0.w, acc0.w);
    acc1.x = fmaf(w, v1.x, acc1.x); acc1.y = fmaf(w, v1.y, acc1.y);
    acc1.z = fmaf(w, v1.z, acc1.z); acc1.w = fmaf(w, v1.w, acc1.w);
  }
  *(float4*)&out[b * 2048 + c0] = acc0;
  *(float4*)&out[b * 2048 + c0 + 4] = acc1;
}

// ---------------- launch ----------------
extern "C" void kernel_launch(void* const* d_in, const int* in_sizes, int n_in,
                              void* d_out, int out_size, void* d_ws, size_t ws_size,
                              hipStream_t stream) {
  const float* x    = (const float*)d_in[0];
  const float* W    = (const float*)d_in[1];
  const float* kcb  = (const float*)d_in[2];
  const float* vcb  = (const float*)d_in[3];
  const float* bias = (const float*)d_in[4];
  const int* key_codes   = (const int*)d_in[5];
  const int* value_codes = (const int*)d_in[6];
  float* out = (float*)d_out;

  float* q   = (float*)d_ws;
  float* lut = q + 1048576;
  float* qsq = lut + 2097152;
  float* csq = qsq + 8192;
  unsigned long long* pcodes = (unsigned long long*)(csq + 2048);
  uint4* poffs = (uint4*)(pcodes + 65536);
  unsigned* cand_d = (unsigned*)(poffs + 65536);
  unsigned short* cand_n = (unsigned short*)(cand_d + 2097152);

  hipLaunchKernelGGL(zero_q_kernel, dim3(1024), dim3(256), 0, stream, (float4*)q);
  hipLaunchKernelGGL(gemm_q_kernel, dim3(16, 16, 4), dim3(256), 0, stream, x, W, q);
  hipLaunchKernelGGL(prep_kernel, dim3(256), dim3(256), 0, stream,
                     q, kcb, key_codes, qsq, csq, pcodes, poffs);
  hipLaunchKernelGGL(lut_kernel, dim3(4, 16, 8), dim3(256), 0, stream,
                     q, kcb, qsq, csq, lut);

  const hipError_t attr_rc = hipFuncSetAttribute(
      (const void*)scan32_kernel, hipFuncAttributeMaxDynamicSharedMemorySize, 135168);
  if (attr_rc == hipSuccess) {
    hipLaunchKernelGGL(scan32_kernel, dim3(1024), dim3(1024), 135168, stream,
                       lut, poffs, cand_d, cand_n);
  } else {
    hipLaunchKernelGGL(scan16_kernel, dim3(1024), dim3(512), 0, stream,
                       lut, pcodes, cand_d, cand_n);
  }

  hipLaunchKernelGGL(select_kernel, dim3(1024), dim3(256), 0, stream,
                     cand_d, cand_n, value_codes, vcb, bias, out);
}

// Round 5
// 236.261 us; speedup vs baseline: 1.2760x; 1.2046x over previous
//
#include <hip/hip_runtime.h>

#define N_ITEMS 65536

// ---------------- Kernel 1: qpart[z] = x @ W (K-chunk 256 per z) ----------------
// 128x128 tile, 512 threads, 8x4 micro-tile (3 ds_read_b128 per 32 FMA ->
// VALU-bound, not LDS-bound like the old 4x4). Grid (8,8,4) = 256 blocks =
// 8 waves/CU = 2/SIMD. Partials to separate buffers: no atomics, no zeroing.
__launch_bounds__(512)
__global__ void gemm_q_kernel(const float* __restrict__ A,
                              const float* __restrict__ W,
                              float* __restrict__ qpart) {
  __shared__ float As[16][132];  // [kk][row]
  __shared__ float Bs[16][132];  // [kk][col]
  const int tid = threadIdx.x;
  const int tx = tid & 31, ty = tid >> 5;   // col-group (4), row-group (8)
  const int rb = blockIdx.y * 128, cb = blockIdx.x * 128;
  const int kz = blockIdx.z * 256;
  // staging: A 128 rows x 16 k (1 float4/thread), B 16 kk x 128 cols
  const int ar = tid >> 2, ac = (tid & 3) << 2;
  const int bk = tid >> 5, bc = (tid & 31) << 2;

  float4 va = *(const float4*)&A[(rb + ar) * 1024 + kz + ac];
  float4 vb = *(const float4*)&W[(kz + bk) * 1024 + cb + bc];

  float acc[8][4] = {};
  for (int k0 = 0; k0 < 256; k0 += 16) {
    As[ac + 0][ar] = va.x; As[ac + 1][ar] = va.y;
    As[ac + 2][ar] = va.z; As[ac + 3][ar] = va.w;
    *(float4*)&Bs[bk][bc] = vb;
    __syncthreads();
    if (k0 + 16 < 256) {  // register double-buffer next tile
      va = *(const float4*)&A[(rb + ar) * 1024 + kz + k0 + 16 + ac];
      vb = *(const float4*)&W[(kz + k0 + 16 + bk) * 1024 + cb + bc];
    }
#pragma unroll
    for (int kk = 0; kk < 16; kk++) {
      const float4 a0 = *(const float4*)&As[kk][ty << 3];
      const float4 a1 = *(const float4*)&As[kk][(ty << 3) + 4];
      const float4 b  = *(const float4*)&Bs[kk][tx << 2];
      const float ar8[8] = {a0.x, a0.y, a0.z, a0.w, a1.x, a1.y, a1.z, a1.w};
      const float br[4] = {b.x, b.y, b.z, b.w};
#pragma unroll
      for (int r = 0; r < 8; r++)
#pragma unroll
        for (int c = 0; c < 4; c++)
          acc[r][c] = fmaf(ar8[r], br[c], acc[r][c]);
    }
    __syncthreads();
  }
  float* outp = qpart + blockIdx.z * 1048576;
#pragma unroll
  for (int r = 0; r < 8; r++)
    *(float4*)&outp[(rb + (ty << 3) + r) * 1024 + cb + (tx << 2)] =
        make_float4(acc[r][0], acc[r][1], acc[r][2], acc[r][3]);
}

// ---------------- Kernel 2: lut + in-register qsq/csq + code packing ----------
// z<8: lut[b][m*256+c] = ||q_seg||^2 + ||cb||^2 - 2*qs.cb, where q is summed
//   from the 4 K-split partials during staging. qsq: each thread's a-frag
//   covers its 4 rows across ALL K=128 -> accumulate a^2 in-register. csq:
//   same with b-frag over its 4 cols. No prep pass, no qsq/csq arrays.
// z==8 plane (64 blocks): pack key_codes -> poffs (scan32 LDS byte offsets)
//   and pcodes (scan16 fallback).
__launch_bounds__(256)
__global__ void lut_kernel(const float* __restrict__ qpart,
                           const float* __restrict__ kcb,
                           const int* __restrict__ key_codes,
                           float* __restrict__ lut,
                           unsigned long long* __restrict__ pcodes,
                           uint4* __restrict__ poffs) {
  if (blockIdx.z == 8) {
    const int g0 = (((int)blockIdx.y * 4 + (int)blockIdx.x) * 256 + (int)threadIdx.x) * 4;
#pragma unroll
    for (int t = 0; t < 4; t++) {
      const int gid = g0 + t;
      unsigned long long p = 0ull;
      unsigned h[8];
#pragma unroll
      for (int j = 0; j < 8; j++) {
        const unsigned c = (unsigned)key_codes[gid * 8 + j] & 255u;
        p |= (unsigned long long)c << (8 * j);
        h[j] = ((unsigned)(j & 3) << 14) | ((c >> 1) << 7) | ((c & 1u) << 1);
      }
      pcodes[gid] = p;
      poffs[gid] = make_uint4(h[0] | (h[1] << 16), h[2] | (h[3] << 16),
                              h[4] | (h[5] << 16), h[6] | (h[7] << 16));
    }
    return;
  }

  __shared__ float As[32][68];
  __shared__ float Bs[32][68];
  const int tid = threadIdx.x;
  const int tx = tid & 15, ty = tid >> 4;
  const int m = blockIdx.z;
  const int rb = blockIdx.y * 64;
  const int cb0 = blockIdx.x * 64;
  float acc[4][4] = {};
  float qa[4] = {}, cs[4] = {};
  for (int k0 = 0; k0 < 128; k0 += 32) {
#pragma unroll
    for (int l = 0; l < 2; l++) {
      const int e = tid + l * 256;
      const int row = e >> 3, c4 = (e & 7) << 2;
      const int qidx = (rb + row) * 1024 + m * 128 + k0 + c4;
      const float4 p0 = *(const float4*)&qpart[qidx];
      const float4 p1 = *(const float4*)&qpart[qidx + 1048576];
      const float4 p2 = *(const float4*)&qpart[qidx + 2097152];
      const float4 p3 = *(const float4*)&qpart[qidx + 3145728];
      const float4 va = make_float4(p0.x + p1.x + p2.x + p3.x,
                                    p0.y + p1.y + p2.y + p3.y,
                                    p0.z + p1.z + p2.z + p3.z,
                                    p0.w + p1.w + p2.w + p3.w);
      As[c4 + 0][row] = va.x; As[c4 + 1][row] = va.y;
      As[c4 + 2][row] = va.z; As[c4 + 3][row] = va.w;
      const float4 vb = *(const float4*)&kcb[(m * 256 + cb0 + row) * 128 + k0 + c4];
      Bs[c4 + 0][row] = vb.x; Bs[c4 + 1][row] = vb.y;
      Bs[c4 + 2][row] = vb.z; Bs[c4 + 3][row] = vb.w;
    }
    __syncthreads();
#pragma unroll
    for (int kk = 0; kk < 32; kk++) {
      const float4 a = *(const float4*)&As[kk][ty << 2];
      const float4 b = *(const float4*)&Bs[kk][tx << 2];
      const float ar[4] = {a.x, a.y, a.z, a.w};
      const float br[4] = {b.x, b.y, b.z, b.w};
#pragma unroll
      for (int r = 0; r < 4; r++)
#pragma unroll
        for (int c = 0; c < 4; c++)
          acc[r][c] = fmaf(ar[r], br[c], acc[r][c]);
#pragma unroll
      for (int r = 0; r < 4; r++) qa[r] = fmaf(ar[r], ar[r], qa[r]);
#pragma unroll
      for (int c = 0; c < 4; c++) cs[c] = fmaf(br[c], br[c], cs[c]);
    }
    __syncthreads();
  }
#pragma unroll
  for (int r = 0; r < 4; r++) {
    const int row = rb + (ty << 2) + r;
    const int col = cb0 + (tx << 2);
    float4 v;
    v.x = qa[r] + cs[0] - 2.0f * acc[r][0];
    v.y = qa[r] + cs[1] - 2.0f * acc[r][1];
    v.z = qa[r] + cs[2] - 2.0f * acc[r][2];
    v.w = qa[r] + cs[3] - 2.0f * acc[r][3];
    *(float4*)&lut[row * 2048 + m * 256 + col] = v;
  }
}

// ---------------- Kernel 3a: ADC scan, 32 single-bank replicas, 1024 thr ----
// At the LDS-issue floor (~79 us model): conflicts verified ~3.3e4.
extern __shared__ char dyn_lds[];

__launch_bounds__(1024)
__global__ void scan32_kernel(const float* __restrict__ lut,
                              const uint4* __restrict__ poffs,
                              unsigned* __restrict__ cand_d,
                              unsigned short* __restrict__ cand_n) {
  char* rep = dyn_lds;                                  // 131072 B
  unsigned* repw = (unsigned*)dyn_lds;
  unsigned* temp = (unsigned*)(dyn_lds + 131072);       // 1024 dwords
  const int tid = threadIdx.x;
  const int b = blockIdx.x;

  if (tid < 512) {
    const float4 v4 = *(const float4*)&lut[b * 2048 + tid * 4];
    float s4 = v4.x + v4.y + v4.z + v4.w;
#pragma unroll
    for (int off = 32; off > 0; off >>= 1) s4 += __shfl_xor(s4, off);
    const float mean = s4 * (1.0f / 256.0f);
    const float vals[4] = {v4.x, v4.y, v4.z, v4.w};
    int qv[4];
#pragma unroll
    for (int k2 = 0; k2 < 4; k2++) {
      float f = (vals[k2] - mean) * 64.0f;
      f = fmaxf(fminf(f, 32000.0f), -32000.0f);
      qv[k2] = (int)rintf(f);
    }
    temp[tid * 2]     = ((unsigned)qv[0] & 0xFFFFu) | ((unsigned)qv[1] << 16);
    temp[tid * 2 + 1] = ((unsigned)qv[2] & 0xFFFFu) | ((unsigned)qv[3] << 16);
  }
  __syncthreads();

  const int r = tid & 31;
  {
    const int chunk = tid >> 5;
    for (int j = 0; j < 32; j += 2) {
      const int idx = chunk * 32 + j;
      const unsigned long long tv = *(const unsigned long long*)&temp[idx];
      repw[idx * 32 + r] = (unsigned)tv;
      repw[(idx + 1) * 32 + r] = (unsigned)(tv >> 32);
    }
  }
  __syncthreads();

  const int rb0 = r * 4;
  const int rb1 = r * 4 + 65536;
  int d0 = 0x7FFFFFFF, d1 = 0x7FFFFFFF;
  int i0 = 0, i1 = 0;

  uint4 oc = poffs[tid];
  uint4 nc = poffs[tid + 1024];
  for (int it = 0; it < 64; it++) {
    const int n = tid + (it << 10);
    uint4 nn2 = nc;
    if (it < 62) nn2 = poffs[n + 2048];
    int s;
    s  = *(const short*)(rep + rb0 + (oc.x & 0xFFFFu));
    s += *(const short*)(rep + rb0 + (oc.x >> 16));
    s += *(const short*)(rep + rb0 + (oc.y & 0xFFFFu));
    s += *(const short*)(rep + rb0 + (oc.y >> 16));
    s += *(const short*)(rep + rb1 + (oc.z & 0xFFFFu));
    s += *(const short*)(rep + rb1 + (oc.z >> 16));
    s += *(const short*)(rep + rb1 + (oc.w & 0xFFFFu));
    s += *(const short*)(rep + rb1 + (oc.w >> 16));
    if (s < d1) {
      if (s < d0) { d1 = d0; i1 = i0; d0 = s; i0 = n; }
      else        { d1 = s; i1 = n; }
    }
    oc = nc; nc = nn2;
  }

  const int base = b * 2048 + tid * 2;
  *(uint2*)&cand_d[base] = make_uint2((unsigned)(d0 + 0x40000000),
                                      (unsigned)(d1 + 0x40000000));
  *(unsigned*)&cand_n[base] = (unsigned)i0 | ((unsigned)i1 << 16);
}

// ---------------- Kernel 3b: fallback 64KB scan ----------------
__launch_bounds__(512)
__global__ void scan16_kernel(const float* __restrict__ lut,
                              const unsigned long long* __restrict__ pcodes,
                              unsigned* __restrict__ cand_d,
                              unsigned short* __restrict__ cand_n) {
  __shared__ short sRep[32768];
  const int tid = threadIdx.x;
  const int b = blockIdx.x;

  const float4 v4 = *(const float4*)&lut[b * 2048 + tid * 4];
  float s4 = v4.x + v4.y + v4.z + v4.w;
#pragma unroll
  for (int off = 32; off > 0; off >>= 1) s4 += __shfl_xor(s4, off);
  const float mean = s4 * (1.0f / 256.0f);

  const float vals[4] = {v4.x, v4.y, v4.z, v4.w};
#pragma unroll
  for (int k2 = 0; k2 < 4; k2++) {
    float f = (vals[k2] - mean) * 64.0f;
    f = fmaxf(fminf(f, 32000.0f), -32000.0f);
    const int iv = (int)rintf(f);
    const unsigned hw = (unsigned)(unsigned short)iv;
    const unsigned wrd = hw | (hw << 16);
    const uint4 wv = make_uint4(wrd, wrd, wrd, wrd);
    const int e = tid * 4 + k2;
    *(uint4*)&((unsigned*)sRep)[e * 8] = wv;
    *(uint4*)&((unsigned*)sRep)[e * 8 + 4] = wv;
  }
  __syncthreads();

  const int r = tid & 15;
  int d0 = 0x7FFFFFFF, d1 = 0x7FFFFFFF, d2 = 0x7FFFFFFF, d3 = 0x7FFFFFFF;
  int i0 = 0, i1 = 0, i2 = 0, i3 = 0;

  unsigned long long c8 = pcodes[tid];
  for (int it = 0; it < 128; it++) {
    const int n = tid + (it << 9);
    unsigned long long nxt = 0ull;
    if (it < 127) nxt = pcodes[n + 512];
    const unsigned lo = (unsigned)c8;
    const unsigned hi = (unsigned)(c8 >> 32);
    int s;
    s  = sRep[(((lo      ) & 255u) << 4) + r        ];
    s += sRep[(((lo >>  8) & 255u) << 4) + r +  4096];
    s += sRep[(((lo >> 16) & 255u) << 4) + r +  8192];
    s += sRep[(((lo >> 24)       ) << 4) + r + 12288];
    s += sRep[(((hi      ) & 255u) << 4) + r + 16384];
    s += sRep[(((hi >>  8) & 255u) << 4) + r + 20480];
    s += sRep[(((hi >> 16) & 255u) << 4) + r + 24576];
    s += sRep[(((hi >> 24)       ) << 4) + r + 28672];
    if (s < d3) {
      if (s < d1) {
        if (s < d0) { d3 = d2; i3 = i2; d2 = d1; i2 = i1; d1 = d0; i1 = i0; d0 = s; i0 = n; }
        else        { d3 = d2; i3 = i2; d2 = d1; i2 = i1; d1 = s; i1 = n; }
      } else {
        if (s < d2) { d3 = d2; i3 = i2; d2 = s; i2 = n; }
        else        { d3 = s; i3 = n; }
      }
    }
    c8 = nxt;
  }

  const int base = b * 2048 + tid * 4;
  const uint4 dv = make_uint4((unsigned)(d0 + 0x40000000), (unsigned)(d1 + 0x40000000),
                              (unsigned)(d2 + 0x40000000), (unsigned)(d3 + 0x40000000));
  *(uint4*)&cand_d[base] = dv;
  const unsigned ni01 = (unsigned)i0 | ((unsigned)i1 << 16);
  const unsigned ni23 = (unsigned)i2 | ((unsigned)i3 << 16);
  *(uint2*)&cand_n[base] = make_uint2(ni01, ni23);
}

// ---------------- Kernel 4: select top-64 + softmax + value gather ----------
__launch_bounds__(256)
__global__ void select_kernel(const unsigned* __restrict__ cand_d,
                              const unsigned short* __restrict__ cand_n,
                              const int* __restrict__ value_codes,
                              const float* __restrict__ vcb,
                              const float* __restrict__ bias,
                              float* __restrict__ out) {
  __shared__ unsigned long long clist[1024];
  __shared__ unsigned sred[256];
  __shared__ int svc[64][8];
  __shared__ float sw[64];
  __shared__ int sidx[64];
  __shared__ int scnt;
  __shared__ unsigned sU;

  const int tid = threadIdx.x;
  const int b = blockIdx.x;

  const uint4 a0 = *(const uint4*)&cand_d[b * 2048 + tid * 8];
  const uint4 a1 = *(const uint4*)&cand_d[b * 2048 + tid * 8 + 4];
  const uint4 nn = *(const uint4*)&cand_n[b * 2048 + tid * 8];
  unsigned dk[8] = {a0.x, a0.y, a0.z, a0.w, a1.x, a1.y, a1.z, a1.w};
  unsigned ni[8] = {nn.x & 0xFFFFu, nn.x >> 16, nn.y & 0xFFFFu, nn.y >> 16,
                    nn.z & 0xFFFFu, nn.z >> 16, nn.w & 0xFFFFu, nn.w >> 16};

  if (tid == 0) scnt = 0;
  unsigned mn = dk[0];
#pragma unroll
  for (int j = 1; j < 8; j++) mn = (dk[j] < mn) ? dk[j] : mn;
  sred[tid] = mn;
  __syncthreads();
  if (tid < 64) {
    unsigned g = sred[tid * 4];
#pragma unroll
    for (int j = 1; j < 4; j++) { const unsigned v = sred[tid * 4 + j]; if (v < g) g = v; }
#pragma unroll
    for (int off = 32; off > 0; off >>= 1) {
      const unsigned o = __shfl_xor(g, off);
      if (o > g) g = o;
    }
    if (tid == 0) sU = g;
  }
  __syncthreads();
  const unsigned U = sU;

  const int lane = tid & 63;
  const unsigned long long lm = (1ull << lane) - 1ull;
#pragma unroll
  for (int j = 0; j < 8; j++) {
    const bool pred = dk[j] <= U;
    const unsigned long long mask = __ballot(pred);
    int base = 0;
    if (lane == 0 && mask) base = atomicAdd(&scnt, __popcll(mask));
    base = __shfl(base, 0);
    if (pred) {
      const int pos = base + __popcll(mask & lm);
      if (pos < 1024) clist[pos] = ((unsigned long long)dk[j] << 32) | ni[j];
    }
  }
  __syncthreads();
  const int cnt = min(scnt, 1024);
  const int SZ = (cnt <= 256) ? 256 : ((cnt <= 512) ? 512 : 1024);
  for (int i = tid; i < SZ; i += 256)
    if (i >= cnt) clist[i] = ~0ull;
  __syncthreads();

  for (int k = 2; k <= SZ; k <<= 1) {
    for (int j = k >> 1; j > 0; j >>= 1) {
      for (int i = tid; i < SZ; i += 256) {
        const int ix = i ^ j;
        if (ix > i) {
          const unsigned long long a = clist[i], c = clist[ix];
          const bool up = ((i & k) == 0);
          if ((a > c) == up) { clist[i] = c; clist[ix] = a; }
        }
      }
      __syncthreads();
    }
  }

  if (tid < 64) {
    const unsigned long long e = clist[tid];
    const int d_int = (int)((unsigned)(e >> 32)) - 0x40000000;
    const float d = (float)d_int * (1.0f / 64.0f);
    const int idx = (int)(e & 0xFFFFFFFFu);
    const float dmin = __shfl(d, 0);
    const float w = __expf(dmin - d);
    float ws = w;
#pragma unroll
    for (int off = 32; off > 0; off >>= 1) ws += __shfl_xor(ws, off);
    sw[tid] = w / ws;
    sidx[tid] = idx;
  }
  __syncthreads();

  for (int i = tid; i < 512; i += 256)
    svc[i >> 3][i & 7] = value_codes[sidx[i >> 3] * 8 + (i & 7)];
  __syncthreads();

  const int c0 = tid << 3;
  const int mv = c0 >> 8;
  const int off = c0 & 255;
  float4 acc0 = *(const float4*)&bias[c0];
  float4 acc1 = *(const float4*)&bias[c0 + 4];
  const float* vbase = vcb + mv * 65536 + off;
  for (int k = 0; k < 64; k++) {
    const float w = sw[k];
    const float* vp = vbase + svc[k][mv] * 256;
    const float4 v0 = *(const float4*)vp;
    const float4 v1 = *(const float4*)(vp + 4);
    acc0.x = fmaf(w, v0.x, acc0.x); acc0.y = fmaf(w, v0.y, acc0.y);
    acc0.z = fmaf(w, v0.z, acc0.z); acc0.w = fmaf(w, v0.w, acc0.w);
    acc1.x = fmaf(w, v1.x, acc1.x); acc1.y = fmaf(w, v1.y, acc1.y);
    acc1.z = fmaf(w, v1.z, acc1.z); acc1.w = fmaf(w, v1.w, acc1.w);
  }
  *(float4*)&out[b * 2048 + c0] = acc0;
  *(float4*)&out[b * 2048 + c0 + 4] = acc1;
}

// ---------------- launch ----------------
extern "C" void kernel_launch(void* const* d_in, const int* in_sizes, int n_in,
                              void* d_out, int out_size, void* d_ws, size_t ws_size,
                              hipStream_t stream) {
  const float* x    = (const float*)d_in[0];
  const float* W    = (const float*)d_in[1];
  const float* kcb  = (const float*)d_in[2];
  const float* vcb  = (const float*)d_in[3];
  const float* bias = (const float*)d_in[4];
  const int* key_codes   = (const int*)d_in[5];
  const int* value_codes = (const int*)d_in[6];
  float* out = (float*)d_out;

  // ws layout (25.5 MB): qpart 16MB | lut 8MB | poffs 1MB | pcodes 0.5MB.
  // cand_d/cand_n ALIAS qpart (qpart last read by lut; cand written by scan
  // afterwards — stream-serial, safe).
  float* qpart = (float*)d_ws;                              // 4 x 1048576 fp32
  float* lut   = qpart + 4194304;                           // 1024 x 2048
  uint4* poffs = (uint4*)(lut + 2097152);                   // 65536 x uint4
  unsigned long long* pcodes = (unsigned long long*)(poffs + 65536);
  unsigned* cand_d = (unsigned*)d_ws;                       // 2M u32 (8MB)
  unsigned short* cand_n = (unsigned short*)(cand_d + 2097152);  // 2M u16 (4MB)

  hipLaunchKernelGGL(gemm_q_kernel, dim3(8, 8, 4), dim3(512), 0, stream,
                     x, W, qpart);
  hipLaunchKernelGGL(lut_kernel, dim3(4, 16, 9), dim3(256), 0, stream,
                     qpart, kcb, key_codes, lut, pcodes, poffs);

  const hipError_t attr_rc = hipFuncSetAttribute(
      (const void*)scan32_kernel, hipFuncAttributeMaxDynamicSharedMemorySize, 135168);
  if (attr_rc == hipSuccess) {
    hipLaunchKernelGGL(scan32_kernel, dim3(1024), dim3(1024), 135168, stream,
                       lut, poffs, cand_d, cand_n);
  } else {
    hipLaunchKernelGGL(scan16_kernel, dim3(1024), dim3(512), 0, stream,
                       lut, pcodes, cand_d, cand_n);
  }

  hipLaunchKernelGGL(select_kernel, dim3(1024), dim3(256), 0, stream,
                     cand_d, cand_n, value_codes, vcb, bias, out);
}